// Round 9
// baseline (134.820 us; speedup 1.0000x reference)
//
#include <hip/hip_runtime.h>
#include <hip/hip_cooperative_groups.h>
#include <stdint.h>

namespace cg = cooperative_groups;

typedef unsigned int u32;
typedef unsigned long long u64;

#define OCC_THR   0.5f
#define RADIUS_F  1.0f
#define MAXP      8192
#define THREADS   512
#define NBLK      128
#define TILE_P    512     // preds per tile (== THREADS)
#define TILE_T    128     // trues per tile
#define PER       8       // true points per thread in match (4096/512)
#define CAP       16      // per-true contiguous row capacity (P(>16) ~ 1e-15)

// ---------------- fused: zero -> build -> match (one dispatch) -------------
// Phase A: grid-stride zero of counts/rowmin (replaces a dispatch; fill
//          kernels cost ~7us each in-graph, measured R3/R7).
// Phase B: all-pairs sweep; candidates (pred_p>=.5, sqrt(d2)<=1) appended to
//          contiguous crows[i*CAP+slot] via global atomic slot; rowmin[i]
//          tracks the row's min key via atomicMin (exact: equals the round-1
//          scan result since all preds start available).
// Phase C: block 0 runs exact greedy via Gale-Shapley deferred acceptance
//          (serial dictatorship == unique stable matching under common
//          pred-side order = true index; availability monotone-shrinking).
//          Round 1 proposes rowmin directly; rescans walk the CONTIGUOUS
//          row (R7-proven; partitioned rescan was R8's +40us regression).
__global__ void __launch_bounds__(THREADS) k_fused(
    const float4* __restrict__ pred, const float4* __restrict__ tru,
    int n_pred, int n_true,
    u32* __restrict__ counts, u64* __restrict__ rowmin,
    u64* __restrict__ crows, float* __restrict__ out)
{
    cg::grid_group grid = cg::this_grid();
    __shared__ float4 st[TILE_T];
    __shared__ u32   s_owner[MAXP];   // 32 KB
    __shared__ int   s_flag;
    __shared__ int   s_numtrue;
    __shared__ float s_rd[8], s_rq[8];
    __shared__ int   s_rc[8];

    const int tid = threadIdx.x;
    const int bid = blockIdx.x;
    const int nb  = gridDim.x;

    // ---- Phase A: zero counters ----
    for (int i = bid * THREADS + tid; i < n_true; i += nb * THREADS) {
        counts[i] = 0u;
        rowmin[i] = ~0ull;
    }
    grid.sync();

    // ---- Phase B: build ----
    const int xt = (n_pred + TILE_P - 1) / TILE_P;
    const int yt = (n_true + TILE_T - 1) / TILE_T;
    for (int t = bid; t < xt * yt; t += nb) {
        const int jx  = (t % xt) * TILE_P + tid;
        const int ti0 = (t / xt) * TILE_T;
        __syncthreads();                      // st reuse across tiles
        for (int q = tid; q < TILE_T; q += THREADS) {
            int i = ti0 + q;
            st[q] = (i < n_true) ? tru[i] : make_float4(1e30f, 1e30f, 1e30f, 0.0f);
        }
        __syncthreads();
        if (jx < n_pred) {
            const float4 p = pred[jx];
            if (p.w >= OCC_THR) {
                const int tmax = min(TILE_T, n_true - ti0);
                for (int q = 0; q < tmax; ++q) {
                    float4 qq = st[q];
                    float dx = qq.x - p.x, dy = qq.y - p.y, dz = qq.z - p.z;
                    float d2 = dx*dx + dy*dy + dz*dz;
                    float d  = sqrtf(d2);
                    if (d <= RADIUS_F) {
                        int i = ti0 + q;
                        u64 key = ((u64)__float_as_uint(d) << 32) | (u32)jx;
                        u32 slot = atomicAdd(&counts[i], 1u);
                        if (slot < (u32)CAP) crows[(size_t)i * CAP + slot] = key;
                        atomicMin(&rowmin[i], key);
                    }
                }
            }
        }
    }
    grid.sync();

    if (bid != 0) return;   // only block 0 matches; no further grid syncs

    // ---- Phase C: deferred-acceptance match ----
    if (tid == 0) s_numtrue = 0;
    for (int j = tid; j < MAXP; j += THREADS) s_owner[j] = 0xFFFFFFFFu;

    float tp[PER]; u32 curj[PER]; float dist[PER]; u64 prop[PER];
    u64 pre[PER]; u32 eff[PER];
    u32 srch = 0;
    int myvalid = 0;

#define INIT_K(k) {                                                          \
        const int i = tid * PER + k;                                         \
        tp[k] = 0.0f; curj[k] = 0xFFFFFFFFu; dist[k] = 0.0f;                 \
        pre[k] = ~0ull; eff[k] = 0;                                          \
        if (i < n_true) {                                                    \
            float4 q = tru[i];                                               \
            tp[k] = q.w;                                                     \
            if (q.w >= OCC_THR) {                                            \
                myvalid++;                                                   \
                u32 c = counts[i];                                           \
                eff[k] = (c > (u32)CAP) ? (u32)CAP : c;                      \
                if (eff[k] > 0u) {                                           \
                    srch |= (1u << k);                                       \
                    pre[k] = rowmin[i];   /* exact round-1 proposal */       \
                }                                                            \
            }                                                                \
        }                                                                    \
    }
    INIT_K(0) INIT_K(1) INIT_K(2) INIT_K(3)
    INIT_K(4) INIT_K(5) INIT_K(6) INIT_K(7)
#undef INIT_K

    if (myvalid) atomicAdd(&s_numtrue, myvalid);
    __syncthreads();

    for (;;) {
        if (tid == 0) s_flag = 0;
        __syncthreads();

#define PROP_K(k) {                                                          \
        prop[k] = ~0ull;                                                     \
        if (srch & (1u << k)) {                                              \
            const u32 i = (u32)(tid * PER + k);                              \
            u64 best;                                                        \
            if (pre[k] != ~0ull) { best = pre[k]; pre[k] = ~0ull; }          \
            else {                                                           \
                const u64* row = crows + (size_t)i * CAP;                    \
                best = ~0ull;                                                \
                for (u32 kk = 0; kk < eff[k]; ++kk) {                        \
                    u64 cd = row[kk];                                        \
                    if (s_owner[(u32)cd] > i && cd < best) best = cd;        \
                }                                                            \
            }                                                                \
            if (best != ~0ull) {                                             \
                atomicMin(&s_owner[(u32)best], i);                           \
                prop[k] = best;                                              \
            } else {                                                         \
                srch &= ~(1u << k);   /* exhausted -> final unmatched */     \
            }                                                                \
        }                                                                    \
    }
        PROP_K(0) PROP_K(1) PROP_K(2) PROP_K(3)
        PROP_K(4) PROP_K(5) PROP_K(6) PROP_K(7)
#undef PROP_K
        __syncthreads();

        bool any = false;
#define ACC_K(k) {                                                           \
        const u32 i = (u32)(tid * PER + k);                                  \
        if (prop[k] != ~0ull) {                                              \
            const u32 j = (u32)prop[k];                                      \
            if (s_owner[j] == i) {        /* tentative hold */               \
                curj[k] = j;                                                 \
                dist[k] = __uint_as_float((u32)(prop[k] >> 32));             \
                srch &= ~(1u << k);                                          \
            } else { any = true; }        /* rejected -> retry */            \
        } else if (curj[k] != 0xFFFFFFFFu) {                                 \
            if (s_owner[curj[k]] != i) {  /* evicted by lower tag */         \
                curj[k] = 0xFFFFFFFFu;                                       \
                srch |= (1u << k);                                           \
                any = true;                                                  \
            }                                                                \
        }                                                                    \
    }
        ACC_K(0) ACC_K(1) ACC_K(2) ACC_K(3)
        ACC_K(4) ACC_K(5) ACC_K(6) ACC_K(7)
#undef ACC_K

        if (any) s_flag = 1;
        __syncthreads();
        if (!s_flag) break;
    }

    // ---- accumulate ----
    float sd = 0.0f, sq = 0.0f; int cnt = 0;
#define SUM_K(k) {                                                           \
        if (curj[k] != 0xFFFFFFFFu) {                                        \
            sd += dist[k];                                                   \
            float pw = pred[curj[k]].w;                                      \
            float df = tp[k] - pw;                                           \
            sq += df * df;                                                   \
            cnt++;                                                           \
        }                                                                    \
    }
    SUM_K(0) SUM_K(1) SUM_K(2) SUM_K(3)
    SUM_K(4) SUM_K(5) SUM_K(6) SUM_K(7)
#undef SUM_K

    for (int o = 32; o > 0; o >>= 1) {
        sd  += __shfl_down(sd,  o, 64);
        sq  += __shfl_down(sq,  o, 64);
        cnt += __shfl_down(cnt, o, 64);
    }
    const int wave = tid >> 6;
    if ((tid & 63) == 0) { s_rd[wave] = sd; s_rq[wave] = sq; s_rc[wave] = cnt; }
    __syncthreads();

    if (tid == 0) {
        float tsd = 0.0f, tsq = 0.0f; int tc = 0;
        for (int w = 0; w < THREADS / 64; ++w) { tsd += s_rd[w]; tsq += s_rq[w]; tc += s_rc[w]; }
        float num_true  = (float)s_numtrue;
        float cnt_f     = (float)tc;
        float unmatched = num_true - cnt_f;
        float denom     = fmaxf(cnt_f, 1.0f);
        bool  has       = tc > 0;
        float spatial   = RADIUS_F * 10.0f * unmatched + (has ? tsd / denom : 0.0f);
        float prob      = unmatched + (has ? tsq / denom : 0.0f);
        out[0] = spatial + prob;
    }
}

// ---------------- launch ----------------
extern "C" void kernel_launch(void* const* d_in, const int* in_sizes, int n_in,
                              void* d_out, int out_size, void* d_ws, size_t ws_size,
                              hipStream_t stream) {
    const float4* pred = (const float4*)d_in[0];
    const float4* tru  = (const float4*)d_in[1];
    int n_pred = in_sizes[0] / 4;
    int n_true = in_sizes[1] / 4;

    // ws layout: counts [n_true u32] | rowmin [n_true u64] | crows [n_true*CAP u64]
    size_t counts_bytes = (size_t)n_true * sizeof(u32);
    size_t off_rmin  = (counts_bytes + 255) & ~(size_t)255;
    size_t off_crows = (off_rmin + (size_t)n_true * 8 + 255) & ~(size_t)255;

    u32* counts = (u32*)d_ws;
    u64* rowmin = (u64*)((char*)d_ws + off_rmin);
    u64* crows  = (u64*)((char*)d_ws + off_crows);
    float* outp = (float*)d_out;

    void* args[] = { (void*)&pred, (void*)&tru, (void*)&n_pred, (void*)&n_true,
                     (void*)&counts, (void*)&rowmin, (void*)&crows, (void*)&outp };
    hipLaunchCooperativeKernel((const void*)k_fused, dim3(NBLK), dim3(THREADS),
                               args, 0, stream);
}

// Round 10
// 56.754 us; speedup vs baseline: 2.3755x; 2.3755x over previous
//
#include <hip/hip_runtime.h>
#include <stdint.h>

typedef unsigned int u32;
typedef unsigned long long u64;

#define OCC_THR   0.5f
#define RADIUS_F  1.0f
#define MAXP      8192
#define THREADS   256
#define TB        8       // trues per build block (block-private rows!)
#define K2_THREADS 512
#define PER       8       // true points per thread in match (4096/512)
#define CAP       16      // per-true contiguous row capacity (P(>16) ~ 1e-15)

// ---------------- Kernel 1: build, zero-free + contiguous ------------------
// Block b owns trues [b*TB, b*TB+TB) and sweeps ALL preds. Candidate rows are
// BLOCK-PRIVATE (LDS), so counts/rowmin/crows are written unconditionally at
// block end: no global zeroing anywhere (poison-safe), no global atomics,
// contiguous rows for the match rescan (R7-proven; partitioned was R5/R8's
// regression). Redundant pred reads (512 x 128KB) hit L2/L3 aggregate BW.
__global__ void __launch_bounds__(THREADS) k_build(
    const float4* __restrict__ pred, const float4* __restrict__ tru,
    int n_pred, int n_true,
    u32* __restrict__ counts, u64* __restrict__ rowmin,
    u64* __restrict__ crows)
{
    __shared__ float4 st[TB];
    __shared__ u32    lcnt[TB];
    __shared__ u64    lmin[TB];
    __shared__ u64    lrow[TB][CAP];

    const int tid = threadIdx.x;
    const int ti0 = blockIdx.x * TB;

    if (tid < TB) {
        int i = ti0 + tid;
        st[tid]   = (i < n_true) ? tru[i] : make_float4(1e30f, 1e30f, 1e30f, 0.0f);
        lcnt[tid] = 0u;
        lmin[tid] = ~0ull;
    }
    __syncthreads();

    for (int j = tid; j < n_pred; j += THREADS) {
        const float4 p = pred[j];
        if (p.w >= OCC_THR) {
#pragma unroll
            for (int t = 0; t < TB; ++t) {
                float4 q = st[t];
                float dx = q.x - p.x, dy = q.y - p.y, dz = q.z - p.z;
                float d2 = dx*dx + dy*dy + dz*dz;
                float d  = sqrtf(d2);
                if (d <= RADIUS_F) {
                    u64 key = ((u64)__float_as_uint(d) << 32) | (u32)j;
                    u32 slot = atomicAdd(&lcnt[t], 1u);
                    if (slot < (u32)CAP) lrow[t][slot] = key;
                    atomicMin(&lmin[t], key);
                }
            }
        }
    }
    __syncthreads();

    if (tid < TB) {
        int i = ti0 + tid;
        if (i < n_true) {
            u32 c = lcnt[tid];
            if (c > (u32)CAP) c = (u32)CAP;
            counts[i] = c;            // unconditional
            rowmin[i] = lmin[tid];    // unconditional (~0ull if empty)
        }
    }
    if (tid < TB * CAP) {
        int t = tid / CAP, s = tid % CAP;
        int i = ti0 + t;
        u32 c = lcnt[t];
        if (c > (u32)CAP) c = (u32)CAP;
        if (i < n_true && (u32)s < c)
            crows[(size_t)i * CAP + s] = lrow[t][s];
    }
}

// ---------------- Kernel 2: exact greedy via deferred acceptance -----------
// Sequential greedy (serial dictatorship by true index) == unique stable
// matching under a common pred-side preference order (the tag), computed
// order-independently by Gale-Shapley: owner[j] = min tag holding j.
// Round 1 proposes rowmin[i] directly (exact: all preds start available);
// rejected/evicted positions rescan their CONTIGUOUS row.
__global__ void __launch_bounds__(K2_THREADS) k_match(
    const float4* __restrict__ pred, const float4* __restrict__ tru,
    int n_true,
    const u32* __restrict__ counts,
    const u64* __restrict__ rowmin,
    const u64* __restrict__ crows,
    float* __restrict__ out)
{
    __shared__ u32   s_owner[MAXP];   // 32 KB
    __shared__ int   s_flag;
    __shared__ int   s_numtrue;
    __shared__ float s_rd[8], s_rq[8];
    __shared__ int   s_rc[8];

    const int tid = threadIdx.x;
    if (tid == 0) s_numtrue = 0;
    for (int j = tid; j < MAXP; j += K2_THREADS) s_owner[j] = 0xFFFFFFFFu;

    // per-position state; ALL accesses use literal indices via macros
    float tp[PER]; u32 curj[PER]; float dist[PER]; u64 prop[PER];
    u64 pre[PER]; u32 eff[PER];
    u32 srch = 0;
    int myvalid = 0;

#define INIT_K(k) {                                                          \
        const int i = tid * PER + k;                                         \
        tp[k] = 0.0f; curj[k] = 0xFFFFFFFFu; dist[k] = 0.0f;                 \
        pre[k] = ~0ull; eff[k] = 0;                                          \
        if (i < n_true) {                                                    \
            float4 q = tru[i];                                               \
            tp[k] = q.w;                                                     \
            if (q.w >= OCC_THR) {                                            \
                myvalid++;                                                   \
                u32 c = counts[i];                                           \
                eff[k] = (c > (u32)CAP) ? (u32)CAP : c;                      \
                if (eff[k] > 0u) {                                           \
                    srch |= (1u << k);                                       \
                    pre[k] = rowmin[i];   /* exact round-1 proposal */       \
                }                                                            \
            }                                                                \
        }                                                                    \
    }
    INIT_K(0) INIT_K(1) INIT_K(2) INIT_K(3)
    INIT_K(4) INIT_K(5) INIT_K(6) INIT_K(7)
#undef INIT_K

    if (myvalid) atomicAdd(&s_numtrue, myvalid);
    __syncthreads();

    // ---- deferred-acceptance rounds ----
    for (;;) {
        if (tid == 0) s_flag = 0;
        __syncthreads();

#define PROP_K(k) {                                                          \
        prop[k] = ~0ull;                                                     \
        if (srch & (1u << k)) {                                              \
            const u32 i = (u32)(tid * PER + k);                              \
            u64 best;                                                        \
            if (pre[k] != ~0ull) { best = pre[k]; pre[k] = ~0ull; }          \
            else {                                                           \
                const u64* row = crows + (size_t)i * CAP;                    \
                best = ~0ull;                                                \
                for (u32 kk = 0; kk < eff[k]; ++kk) {                        \
                    u64 cd = row[kk];                                        \
                    if (s_owner[(u32)cd] > i && cd < best) best = cd;        \
                }                                                            \
            }                                                                \
            if (best != ~0ull) {                                             \
                atomicMin(&s_owner[(u32)best], i);                           \
                prop[k] = best;                                              \
            } else {                                                         \
                srch &= ~(1u << k);   /* exhausted -> final unmatched */     \
            }                                                                \
        }                                                                    \
    }
        PROP_K(0) PROP_K(1) PROP_K(2) PROP_K(3)
        PROP_K(4) PROP_K(5) PROP_K(6) PROP_K(7)
#undef PROP_K
        __syncthreads();

        bool any = false;
#define ACC_K(k) {                                                           \
        const u32 i = (u32)(tid * PER + k);                                  \
        if (prop[k] != ~0ull) {                                              \
            const u32 j = (u32)prop[k];                                      \
            if (s_owner[j] == i) {        /* tentative hold */               \
                curj[k] = j;                                                 \
                dist[k] = __uint_as_float((u32)(prop[k] >> 32));             \
                srch &= ~(1u << k);                                          \
            } else { any = true; }        /* rejected -> retry */            \
        } else if (curj[k] != 0xFFFFFFFFu) {                                 \
            if (s_owner[curj[k]] != i) {  /* evicted by lower tag */         \
                curj[k] = 0xFFFFFFFFu;                                       \
                srch |= (1u << k);                                           \
                any = true;                                                  \
            }                                                                \
        }                                                                    \
    }
        ACC_K(0) ACC_K(1) ACC_K(2) ACC_K(3)
        ACC_K(4) ACC_K(5) ACC_K(6) ACC_K(7)
#undef ACC_K

        if (any) s_flag = 1;
        __syncthreads();
        if (!s_flag) break;
    }

    // ---- accumulate ----
    float sd = 0.0f, sq = 0.0f; int cnt = 0;
#define SUM_K(k) {                                                           \
        if (curj[k] != 0xFFFFFFFFu) {                                        \
            sd += dist[k];                                                   \
            float pw = pred[curj[k]].w;                                      \
            float df = tp[k] - pw;                                           \
            sq += df * df;                                                   \
            cnt++;                                                           \
        }                                                                    \
    }
    SUM_K(0) SUM_K(1) SUM_K(2) SUM_K(3)
    SUM_K(4) SUM_K(5) SUM_K(6) SUM_K(7)
#undef SUM_K

    for (int o = 32; o > 0; o >>= 1) {
        sd  += __shfl_down(sd,  o, 64);
        sq  += __shfl_down(sq,  o, 64);
        cnt += __shfl_down(cnt, o, 64);
    }
    const int wave = tid >> 6;
    if ((tid & 63) == 0) { s_rd[wave] = sd; s_rq[wave] = sq; s_rc[wave] = cnt; }
    __syncthreads();

    if (tid == 0) {
        float tsd = 0.0f, tsq = 0.0f; int tc = 0;
        for (int w = 0; w < K2_THREADS / 64; ++w) { tsd += s_rd[w]; tsq += s_rq[w]; tc += s_rc[w]; }
        float num_true  = (float)s_numtrue;
        float cnt_f     = (float)tc;
        float unmatched = num_true - cnt_f;
        float denom     = fmaxf(cnt_f, 1.0f);
        bool  has       = tc > 0;
        float spatial   = RADIUS_F * 10.0f * unmatched + (has ? tsd / denom : 0.0f);
        float prob      = unmatched + (has ? tsq / denom : 0.0f);
        out[0] = spatial + prob;
    }
}

// ---------------- launch ----------------
extern "C" void kernel_launch(void* const* d_in, const int* in_sizes, int n_in,
                              void* d_out, int out_size, void* d_ws, size_t ws_size,
                              hipStream_t stream) {
    const float4* pred = (const float4*)d_in[0];
    const float4* tru  = (const float4*)d_in[1];
    const int n_pred = in_sizes[0] / 4;
    const int n_true = in_sizes[1] / 4;

    // ws layout: counts [n_true u32] | rowmin [n_true u64] | crows [n_true*CAP u64]
    size_t counts_bytes = (size_t)n_true * sizeof(u32);
    size_t off_rmin  = (counts_bytes + 255) & ~(size_t)255;
    size_t off_crows = (off_rmin + (size_t)n_true * 8 + 255) & ~(size_t)255;

    u32* counts = (u32*)d_ws;
    u64* rowmin = (u64*)((char*)d_ws + off_rmin);
    u64* crows  = (u64*)((char*)d_ws + off_crows);

    k_build<<<(n_true + TB - 1) / TB, THREADS, 0, stream>>>(
        pred, tru, n_pred, n_true, counts, rowmin, crows);
    k_match<<<1, K2_THREADS, 0, stream>>>(
        pred, tru, n_true, counts, rowmin, crows, (float*)d_out);
}

// Round 11
// 55.195 us; speedup vs baseline: 2.4426x; 1.0282x over previous
//
#include <hip/hip_runtime.h>
#include <stdint.h>

typedef unsigned int u32;
typedef unsigned long long u64;

#define OCC_THR   0.5f
#define RADIUS_F  1.0f
#define MAXP      8192
#define K1_TT     128     // trues per y-tile in k_build
#define K2_THREADS 512
#define PER       8       // true points per thread in match (4096/512)
#define CAP       16      // per-true contiguous row capacity (P(>16) ~ 1e-15)

// ---------------- Kernel 0: zero counters + rowmin (custom, NOT memset) ----
// rocclr fillBufferAligned dispatches are pathological in this graph context;
// a plain store kernel is ~2-3 us (R3/R7 measured delta).
__global__ void __launch_bounds__(256) k_zero(u32* __restrict__ counts,
                                              u64* __restrict__ rowmin, int n) {
    const int i = blockIdx.x * 256 + threadIdx.x;
    if (i < n) { counts[i] = 0u; rowmin[i] = ~0ull; }
}

// ---------------- Kernel 1: 2D-tiled build -> contiguous rows + rowmin -----
// Grid (32,32): block handles preds [bx*256,+256) x trues [by*128,+128).
// Pred register-resident, trues staged in LDS -> pred load amortized over 128
// pairs; 1024 blocks = 4 waves/SIMD (R10's TB build had 2 and was 43.7us).
// Candidates appended to CONTIGUOUS crows[i*CAP+slot] via global atomic slot
// (R7-proven; avg 1.35 appends/row). rowmin[i] = min key via LDS min + one
// sparse global atomicMin per (row, block) -> exact round-1 proposal.
__global__ void __launch_bounds__(256) k_build(
    const float4* __restrict__ pred, const float4* __restrict__ tru,
    int n_pred, int n_true,
    u32* __restrict__ counts, u64* __restrict__ rowmin,
    u64* __restrict__ crows)
{
    __shared__ float4 st[K1_TT];
    __shared__ u64    lmin[K1_TT];
    const int tid = threadIdx.x;
    const int j   = blockIdx.x * 256 + tid;
    const int ti0 = blockIdx.y * K1_TT;

    for (int t = tid; t < K1_TT; t += 256) {
        int i = ti0 + t;
        st[t]   = (i < n_true) ? tru[i] : make_float4(1e30f, 1e30f, 1e30f, 0.0f);
        lmin[t] = ~0ull;
    }
    __syncthreads();

    const int tmax = min(K1_TT, n_true - ti0);
    if (j < n_pred) {
        const float4 p = pred[j];
        if (p.w >= OCC_THR) {
            for (int t = 0; t < tmax; ++t) {
                float4 q = st[t];
                float dx = q.x - p.x, dy = q.y - p.y, dz = q.z - p.z;
                float d2 = dx*dx + dy*dy + dz*dz;
                float d  = sqrtf(d2);           // keep sqrt: boundary ties
                if (d <= RADIUS_F) {            // match ref's post-sqrt compare
                    int i = ti0 + t;
                    u64 key = ((u64)__float_as_uint(d) << 32) | (u32)j;
                    u32 slot = atomicAdd(&counts[i], 1u);
                    if (slot < (u32)CAP) crows[(size_t)i * CAP + slot] = key;
                    atomicMin(&lmin[t], key);
                }
            }
        }
    }
    __syncthreads();

    for (int t = tid; t < tmax; t += 256)
        if (lmin[t] != ~0ull)
            atomicMin(&rowmin[ti0 + t], lmin[t]);   // sparse (~2.6 per block)
}

// ---------------- Kernel 2: exact greedy via deferred acceptance -----------
// (R10 verbatim - measured ~9-10us.) Sequential greedy == unique stable
// matching under common pred-side order (true index); Gale-Shapley computes
// it order-independently: owner[j] = min tag holding j. Round 1 proposes
// rowmin[i]; rejected/evicted positions rescan their CONTIGUOUS row.
__global__ void __launch_bounds__(K2_THREADS) k_match(
    const float4* __restrict__ pred, const float4* __restrict__ tru,
    int n_true,
    const u32* __restrict__ counts,
    const u64* __restrict__ rowmin,
    const u64* __restrict__ crows,
    float* __restrict__ out)
{
    __shared__ u32   s_owner[MAXP];   // 32 KB
    __shared__ int   s_flag;
    __shared__ int   s_numtrue;
    __shared__ float s_rd[8], s_rq[8];
    __shared__ int   s_rc[8];

    const int tid = threadIdx.x;
    if (tid == 0) s_numtrue = 0;
    for (int j = tid; j < MAXP; j += K2_THREADS) s_owner[j] = 0xFFFFFFFFu;

    float tp[PER]; u32 curj[PER]; float dist[PER]; u64 prop[PER];
    u64 pre[PER]; u32 eff[PER];
    u32 srch = 0;
    int myvalid = 0;

#define INIT_K(k) {                                                          \
        const int i = tid * PER + k;                                         \
        tp[k] = 0.0f; curj[k] = 0xFFFFFFFFu; dist[k] = 0.0f;                 \
        pre[k] = ~0ull; eff[k] = 0;                                          \
        if (i < n_true) {                                                    \
            float4 q = tru[i];                                               \
            tp[k] = q.w;                                                     \
            if (q.w >= OCC_THR) {                                            \
                myvalid++;                                                   \
                u32 c = counts[i];                                           \
                eff[k] = (c > (u32)CAP) ? (u32)CAP : c;                      \
                if (eff[k] > 0u) {                                           \
                    srch |= (1u << k);                                       \
                    pre[k] = rowmin[i];   /* exact round-1 proposal */       \
                }                                                            \
            }                                                                \
        }                                                                    \
    }
    INIT_K(0) INIT_K(1) INIT_K(2) INIT_K(3)
    INIT_K(4) INIT_K(5) INIT_K(6) INIT_K(7)
#undef INIT_K

    if (myvalid) atomicAdd(&s_numtrue, myvalid);
    __syncthreads();

    for (;;) {
        if (tid == 0) s_flag = 0;
        __syncthreads();

#define PROP_K(k) {                                                          \
        prop[k] = ~0ull;                                                     \
        if (srch & (1u << k)) {                                              \
            const u32 i = (u32)(tid * PER + k);                              \
            u64 best;                                                        \
            if (pre[k] != ~0ull) { best = pre[k]; pre[k] = ~0ull; }          \
            else {                                                           \
                const u64* row = crows + (size_t)i * CAP;                    \
                best = ~0ull;                                                \
                for (u32 kk = 0; kk < eff[k]; ++kk) {                        \
                    u64 cd = row[kk];                                        \
                    if (s_owner[(u32)cd] > i && cd < best) best = cd;        \
                }                                                            \
            }                                                                \
            if (best != ~0ull) {                                             \
                atomicMin(&s_owner[(u32)best], i);                           \
                prop[k] = best;                                              \
            } else {                                                         \
                srch &= ~(1u << k);   /* exhausted -> final unmatched */     \
            }                                                                \
        }                                                                    \
    }
        PROP_K(0) PROP_K(1) PROP_K(2) PROP_K(3)
        PROP_K(4) PROP_K(5) PROP_K(6) PROP_K(7)
#undef PROP_K
        __syncthreads();

        bool any = false;
#define ACC_K(k) {                                                           \
        const u32 i = (u32)(tid * PER + k);                                  \
        if (prop[k] != ~0ull) {                                              \
            const u32 j = (u32)prop[k];                                      \
            if (s_owner[j] == i) {        /* tentative hold */               \
                curj[k] = j;                                                 \
                dist[k] = __uint_as_float((u32)(prop[k] >> 32));             \
                srch &= ~(1u << k);                                          \
            } else { any = true; }        /* rejected -> retry */            \
        } else if (curj[k] != 0xFFFFFFFFu) {                                 \
            if (s_owner[curj[k]] != i) {  /* evicted by lower tag */         \
                curj[k] = 0xFFFFFFFFu;                                       \
                srch |= (1u << k);                                           \
                any = true;                                                  \
            }                                                                \
        }                                                                    \
    }
        ACC_K(0) ACC_K(1) ACC_K(2) ACC_K(3)
        ACC_K(4) ACC_K(5) ACC_K(6) ACC_K(7)
#undef ACC_K

        if (any) s_flag = 1;
        __syncthreads();
        if (!s_flag) break;
    }

    // ---- accumulate ----
    float sd = 0.0f, sq = 0.0f; int cnt = 0;
#define SUM_K(k) {                                                           \
        if (curj[k] != 0xFFFFFFFFu) {                                        \
            sd += dist[k];                                                   \
            float pw = pred[curj[k]].w;                                      \
            float df = tp[k] - pw;                                           \
            sq += df * df;                                                   \
            cnt++;                                                           \
        }                                                                    \
    }
    SUM_K(0) SUM_K(1) SUM_K(2) SUM_K(3)
    SUM_K(4) SUM_K(5) SUM_K(6) SUM_K(7)
#undef SUM_K

    for (int o = 32; o > 0; o >>= 1) {
        sd  += __shfl_down(sd,  o, 64);
        sq  += __shfl_down(sq,  o, 64);
        cnt += __shfl_down(cnt, o, 64);
    }
    const int wave = tid >> 6;
    if ((tid & 63) == 0) { s_rd[wave] = sd; s_rq[wave] = sq; s_rc[wave] = cnt; }
    __syncthreads();

    if (tid == 0) {
        float tsd = 0.0f, tsq = 0.0f; int tc = 0;
        for (int w = 0; w < K2_THREADS / 64; ++w) { tsd += s_rd[w]; tsq += s_rq[w]; tc += s_rc[w]; }
        float num_true  = (float)s_numtrue;
        float cnt_f     = (float)tc;
        float unmatched = num_true - cnt_f;
        float denom     = fmaxf(cnt_f, 1.0f);
        bool  has       = tc > 0;
        float spatial   = RADIUS_F * 10.0f * unmatched + (has ? tsd / denom : 0.0f);
        float prob      = unmatched + (has ? tsq / denom : 0.0f);
        out[0] = spatial + prob;
    }
}

// ---------------- launch ----------------
extern "C" void kernel_launch(void* const* d_in, const int* in_sizes, int n_in,
                              void* d_out, int out_size, void* d_ws, size_t ws_size,
                              hipStream_t stream) {
    const float4* pred = (const float4*)d_in[0];
    const float4* tru  = (const float4*)d_in[1];
    const int n_pred = in_sizes[0] / 4;
    const int n_true = in_sizes[1] / 4;

    // ws layout: counts [n_true u32] | rowmin [n_true u64] | crows [n_true*CAP u64]
    size_t counts_bytes = (size_t)n_true * sizeof(u32);
    size_t off_rmin  = (counts_bytes + 255) & ~(size_t)255;
    size_t off_crows = (off_rmin + (size_t)n_true * 8 + 255) & ~(size_t)255;

    u32* counts = (u32*)d_ws;
    u64* rowmin = (u64*)((char*)d_ws + off_rmin);
    u64* crows  = (u64*)((char*)d_ws + off_crows);

    k_zero<<<(n_true + 255) / 256, 256, 0, stream>>>(counts, rowmin, n_true);

    dim3 g1((n_pred + 255) / 256, (n_true + K1_TT - 1) / K1_TT);
    k_build<<<g1, 256, 0, stream>>>(pred, tru, n_pred, n_true,
                                    counts, rowmin, crows);

    k_match<<<1, K2_THREADS, 0, stream>>>(pred, tru, n_true,
                                          counts, rowmin, crows, (float*)d_out);
}

// Round 12
// 38.469 us; speedup vs baseline: 3.5047x; 1.4348x over previous
//
#include <hip/hip_runtime.h>
#include <stdint.h>

typedef unsigned int u32;
typedef unsigned long long u64;

#define OCC_THR   0.5f
#define RADIUS_F  1.0f
#define D2_PRE    1.000002f   // d2 > this  =>  sqrtf(d2) > 1.0f guaranteed
#define MAXP      8192
#define BTHREADS  256
#define TB        4       // trues per build block -> n_true/TB = 1024 blocks
#define K2_THREADS 512
#define PER       8       // true points per thread in match (4096/512)
#define CAP       16      // per-true contiguous row capacity (P(>16) ~ 1e-18)

// ---------------- Kernel 1: zero-free block-private build ------------------
// Block b owns trues [b*TB, b*TB+TB) (REGISTER-resident) and sweeps ALL preds
// (L2-resident, coalesced). Rows/counters/rowmin live in block-private LDS and
// are flushed UNCONDITIONALLY -> no zeroing dispatch, no global atomics,
// contiguous rows (R7-proven layout). 1024 blocks = 4/CU (R10's 512 was the
// occupancy mistake). Invalid preds are neutralized via cndmask (px=1e30),
// not a divergent branch; sqrtf runs only behind the exact d2 prefilter.
__global__ void __launch_bounds__(BTHREADS) k_build(
    const float4* __restrict__ pred, const float4* __restrict__ tru,
    int n_pred, int n_true,
    u32* __restrict__ counts, u64* __restrict__ rowmin,
    u64* __restrict__ crows)
{
    __shared__ float4 st[TB];
    __shared__ u32    lcnt[TB];
    __shared__ u64    lmin[TB];
    __shared__ u64    lrow[TB][CAP];

    const int tid = threadIdx.x;
    const int ti0 = blockIdx.x * TB;

    if (tid < TB) {
        int i = ti0 + tid;
        st[tid]   = (i < n_true) ? tru[i] : make_float4(1e30f, 1e30f, 1e30f, 0.0f);
        lcnt[tid] = 0u;
        lmin[tid] = ~0ull;
    }
    __syncthreads();

    const float4 q0 = st[0], q1 = st[1], q2 = st[2], q3 = st[3];

#define TEST_T(t, q) {                                                       \
        float dx = (q).x - px, dy = (q).y - p.y, dz = (q).z - p.z;           \
        float d2 = dx*dx + dy*dy + dz*dz;                                    \
        if (d2 <= D2_PRE) {                                                  \
            float d = sqrtf(d2);                                             \
            if (d <= RADIUS_F) {      /* exact post-sqrt compare (ref) */    \
                u64 key = ((u64)__float_as_uint(d) << 32) | (u32)j;          \
                u32 slot = atomicAdd(&lcnt[t], 1u);                          \
                if (slot < (u32)CAP) lrow[t][slot] = key;                    \
                atomicMin(&lmin[t], key);                                    \
            }                                                                \
        }                                                                    \
    }

    for (int j = tid; j < n_pred; j += BTHREADS) {
        const float4 p = pred[j];
        const float px = (p.w >= OCC_THR) ? p.x : 1e30f;   // cndmask, no branch
        TEST_T(0, q0) TEST_T(1, q1) TEST_T(2, q2) TEST_T(3, q3)
    }
#undef TEST_T
    __syncthreads();

    if (tid < TB) {
        int i = ti0 + tid;
        if (i < n_true) {
            u32 c = lcnt[tid];
            if (c > (u32)CAP) c = (u32)CAP;
            counts[i] = c;            // unconditional -> poison-safe
            rowmin[i] = lmin[tid];    // unconditional (~0ull if empty)
        }
    }
    if (tid < TB * CAP) {
        int t = tid >> 4, s = tid & 15;
        int i = ti0 + t;
        u32 c = lcnt[t];
        if (c > (u32)CAP) c = (u32)CAP;
        if (i < n_true && (u32)s < c)
            crows[(size_t)i * CAP + s] = lrow[t][s];
    }
}

// ---------------- Kernel 2: exact greedy via deferred acceptance -----------
// (R10/R11 verbatim, ~9-10us measured.) Sequential greedy == unique stable
// matching under common pred-side order (true index); Gale-Shapley computes
// it order-independently: owner[j] = min tag holding j. Round 1 proposes
// rowmin[i]; rejected/evicted positions rescan their CONTIGUOUS row.
__global__ void __launch_bounds__(K2_THREADS) k_match(
    const float4* __restrict__ pred, const float4* __restrict__ tru,
    int n_true,
    const u32* __restrict__ counts,
    const u64* __restrict__ rowmin,
    const u64* __restrict__ crows,
    float* __restrict__ out)
{
    __shared__ u32   s_owner[MAXP];   // 32 KB
    __shared__ int   s_flag;
    __shared__ int   s_numtrue;
    __shared__ float s_rd[8], s_rq[8];
    __shared__ int   s_rc[8];

    const int tid = threadIdx.x;
    if (tid == 0) s_numtrue = 0;
    for (int j = tid; j < MAXP; j += K2_THREADS) s_owner[j] = 0xFFFFFFFFu;

    float tp[PER]; u32 curj[PER]; float dist[PER]; u64 prop[PER];
    u64 pre[PER]; u32 eff[PER];
    u32 srch = 0;
    int myvalid = 0;

#define INIT_K(k) {                                                          \
        const int i = tid * PER + k;                                         \
        tp[k] = 0.0f; curj[k] = 0xFFFFFFFFu; dist[k] = 0.0f;                 \
        pre[k] = ~0ull; eff[k] = 0;                                          \
        if (i < n_true) {                                                    \
            float4 q = tru[i];                                               \
            tp[k] = q.w;                                                     \
            if (q.w >= OCC_THR) {                                            \
                myvalid++;                                                   \
                u32 c = counts[i];                                           \
                eff[k] = (c > (u32)CAP) ? (u32)CAP : c;                      \
                if (eff[k] > 0u) {                                           \
                    srch |= (1u << k);                                       \
                    pre[k] = rowmin[i];   /* exact round-1 proposal */       \
                }                                                            \
            }                                                                \
        }                                                                    \
    }
    INIT_K(0) INIT_K(1) INIT_K(2) INIT_K(3)
    INIT_K(4) INIT_K(5) INIT_K(6) INIT_K(7)
#undef INIT_K

    if (myvalid) atomicAdd(&s_numtrue, myvalid);
    __syncthreads();

    for (;;) {
        if (tid == 0) s_flag = 0;
        __syncthreads();

#define PROP_K(k) {                                                          \
        prop[k] = ~0ull;                                                     \
        if (srch & (1u << k)) {                                              \
            const u32 i = (u32)(tid * PER + k);                              \
            u64 best;                                                        \
            if (pre[k] != ~0ull) { best = pre[k]; pre[k] = ~0ull; }          \
            else {                                                           \
                const u64* row = crows + (size_t)i * CAP;                    \
                best = ~0ull;                                                \
                for (u32 kk = 0; kk < eff[k]; ++kk) {                        \
                    u64 cd = row[kk];                                        \
                    if (s_owner[(u32)cd] > i && cd < best) best = cd;        \
                }                                                            \
            }                                                                \
            if (best != ~0ull) {                                             \
                atomicMin(&s_owner[(u32)best], i);                           \
                prop[k] = best;                                              \
            } else {                                                         \
                srch &= ~(1u << k);   /* exhausted -> final unmatched */     \
            }                                                                \
        }                                                                    \
    }
        PROP_K(0) PROP_K(1) PROP_K(2) PROP_K(3)
        PROP_K(4) PROP_K(5) PROP_K(6) PROP_K(7)
#undef PROP_K
        __syncthreads();

        bool any = false;
#define ACC_K(k) {                                                           \
        const u32 i = (u32)(tid * PER + k);                                  \
        if (prop[k] != ~0ull) {                                              \
            const u32 j = (u32)prop[k];                                      \
            if (s_owner[j] == i) {        /* tentative hold */               \
                curj[k] = j;                                                 \
                dist[k] = __uint_as_float((u32)(prop[k] >> 32));             \
                srch &= ~(1u << k);                                          \
            } else { any = true; }        /* rejected -> retry */            \
        } else if (curj[k] != 0xFFFFFFFFu) {                                 \
            if (s_owner[curj[k]] != i) {  /* evicted by lower tag */         \
                curj[k] = 0xFFFFFFFFu;                                       \
                srch |= (1u << k);                                           \
                any = true;                                                  \
            }                                                                \
        }                                                                    \
    }
        ACC_K(0) ACC_K(1) ACC_K(2) ACC_K(3)
        ACC_K(4) ACC_K(5) ACC_K(6) ACC_K(7)
#undef ACC_K

        if (any) s_flag = 1;
        __syncthreads();
        if (!s_flag) break;
    }

    // ---- accumulate ----
    float sd = 0.0f, sq = 0.0f; int cnt = 0;
#define SUM_K(k) {                                                           \
        if (curj[k] != 0xFFFFFFFFu) {                                        \
            sd += dist[k];                                                   \
            float pw = pred[curj[k]].w;                                      \
            float df = tp[k] - pw;                                           \
            sq += df * df;                                                   \
            cnt++;                                                           \
        }                                                                    \
    }
    SUM_K(0) SUM_K(1) SUM_K(2) SUM_K(3)
    SUM_K(4) SUM_K(5) SUM_K(6) SUM_K(7)
#undef SUM_K

    for (int o = 32; o > 0; o >>= 1) {
        sd  += __shfl_down(sd,  o, 64);
        sq  += __shfl_down(sq,  o, 64);
        cnt += __shfl_down(cnt, o, 64);
    }
    const int wave = tid >> 6;
    if ((tid & 63) == 0) { s_rd[wave] = sd; s_rq[wave] = sq; s_rc[wave] = cnt; }
    __syncthreads();

    if (tid == 0) {
        float tsd = 0.0f, tsq = 0.0f; int tc = 0;
        for (int w = 0; w < K2_THREADS / 64; ++w) { tsd += s_rd[w]; tsq += s_rq[w]; tc += s_rc[w]; }
        float num_true  = (float)s_numtrue;
        float cnt_f     = (float)tc;
        float unmatched = num_true - cnt_f;
        float denom     = fmaxf(cnt_f, 1.0f);
        bool  has       = tc > 0;
        float spatial   = RADIUS_F * 10.0f * unmatched + (has ? tsd / denom : 0.0f);
        float prob      = unmatched + (has ? tsq / denom : 0.0f);
        out[0] = spatial + prob;
    }
}

// ---------------- launch ----------------
extern "C" void kernel_launch(void* const* d_in, const int* in_sizes, int n_in,
                              void* d_out, int out_size, void* d_ws, size_t ws_size,
                              hipStream_t stream) {
    const float4* pred = (const float4*)d_in[0];
    const float4* tru  = (const float4*)d_in[1];
    const int n_pred = in_sizes[0] / 4;
    const int n_true = in_sizes[1] / 4;

    // ws layout: counts [n_true u32] | rowmin [n_true u64] | crows [n_true*CAP u64]
    size_t counts_bytes = (size_t)n_true * sizeof(u32);
    size_t off_rmin  = (counts_bytes + 255) & ~(size_t)255;
    size_t off_crows = (off_rmin + (size_t)n_true * 8 + 255) & ~(size_t)255;

    u32* counts = (u32*)d_ws;
    u64* rowmin = (u64*)((char*)d_ws + off_rmin);
    u64* crows  = (u64*)((char*)d_ws + off_crows);

    k_build<<<(n_true + TB - 1) / TB, BTHREADS, 0, stream>>>(
        pred, tru, n_pred, n_true, counts, rowmin, crows);
    k_match<<<1, K2_THREADS, 0, stream>>>(
        pred, tru, n_true, counts, rowmin, crows, (float*)d_out);
}